// Round 5
// baseline (184.851 us; speedup 1.0000x reference)
//
#include <hip/hip_runtime.h>
#include <hip/hip_bf16.h>
#include <stdint.h>

// out = softmax(relu(X @ new_weight)), new_weight = weight + MLP(feat)[...,0].
// hidden features collapse analytically to bit features of (n,m); layer-1 is
// rank-1 + separable -> per-row table rn[n][10] + per-col table cm[m][10],
// computed inline per k_nw block.
// R14 = R13 + X READ DIRECTLY BY GEMM (Ah intermediate deleted):
//   gemm stages A from X f32 with in-register RNE f16 convert (reg-staged
//   ds_write path, A(it+1) loads issued before the compute barrier so their
//   latency hides under MFMA). Removes the k_nw cast pass entirely:
//   HBM delta = -(16.8 X-read + 8 Ah-write + 8 Ah-read) + 16.8 X-read-in-gemm
//   = -16 MB ~= -2.5us. Numerics bitwise-identical to R13 (same RNE casts,
//   same MFMA sequence): absmax 3.9e-3 (threshold 1.2e-2).
// R13: fp16 intermediate C (Ch 8 MB) -> matched prediction, -2.2us.
// R11: cooperative fusion rejected (+139us grid-sync stall). Accounting:
//   ~148.5us = 3 harness poison fills is the floor; our kernels own ~27us.
// GEMM core: single-phase fp16 MFMA, tile 128x64, BK=64, grid 512, XCD
//   swizzle, XOR-swizzled LDS chunks.
//
// 4 dispatches: k_pre (sums) -> k_nw (MLP only, 1024 blocks) -> k_gemm14 ->
//   k_softmax3.
//
// ws layout (bytes):
//   rs      @ 0        : f32[1024]          row sums of weight
//   cs_part @ 4096     : f32[64][1024]      per-block partial col sums
//   Bt      @ 266240   : f16[1024][1024]    new_weight^T         (2 MB)
//   (Ah region @2363392 unused as of R14)
//   Ch      @ 10752000 : f16[4096][1024]    f16 logits           (8 MB)

#define RS_OFF      0
#define CSPART_OFF  4096
#define BT_OFF      266240
#define CH_OFF      10752000

typedef __attribute__((ext_vector_type(8))) _Float16 f16x8;
typedef __attribute__((ext_vector_type(4))) float f32x4;

__device__ __forceinline__ unsigned short f2h(float x) {
    _Float16 h = (_Float16)x;            // RNE
    unsigned short u;
    __builtin_memcpy(&u, &h, 2);
    return u;
}
__device__ __forceinline__ float h2f(unsigned short u) {
    _Float16 h;
    __builtin_memcpy(&h, &u, 2);
    return (float)h;
}
__device__ __forceinline__ void gld16(const void* g, void* l) {
    __builtin_amdgcn_global_load_lds(
        (const __attribute__((address_space(1))) unsigned*)g,
        (__attribute__((address_space(3))) unsigned*)l, 16, 0, 0);
}

// ---------------------------------------------------------------------------
// K1: row sums (wave per 4 rows, shuffle) + 64 partial colsum vectors.
__global__ __launch_bounds__(256) void k_pre(const float* __restrict__ w,
        float* __restrict__ rs, float* __restrict__ cs_part) {
    __shared__ float part[4][1024];
    int t = threadIdx.x;
    int lane = t & 63, wv = t >> 6;
    int r0 = blockIdx.x * 16 + wv * 4;
    float ccol[16];
    #pragma unroll
    for (int j = 0; j < 16; ++j) ccol[j] = 0.f;
    #pragma unroll
    for (int rr = 0; rr < 4; ++rr) {
        int row = r0 + rr;
        float rsum = 0.f;
        #pragma unroll
        for (int j = 0; j < 16; ++j) {
            float v = w[(size_t)row * 1024 + j * 64 + lane];
            ccol[j] += v;
            rsum += v;
        }
        #pragma unroll
        for (int o = 32; o; o >>= 1) rsum += __shfl_down(rsum, o);
        if (lane == 0) rs[row] = rsum;
    }
    #pragma unroll
    for (int j = 0; j < 16; ++j) part[wv][j * 64 + lane] = ccol[j];
    __syncthreads();
    #pragma unroll
    for (int j = 0; j < 4; ++j) {
        int c = t + j * 256;
        cs_part[(size_t)blockIdx.x * 1024 + c] =
            part[0][c] + part[1][c] + part[2][c] + part[3][c];
    }
}

// ---------------------------------------------------------------------------
// K2 (R14): new_weight MLP on 32x32 tiles (inline rn/cm tables + colsum
// reduction), writing TRANSPOSED fp16 Bt[m][n]. 1024 blocks (cast pass
// removed -- gemm reads X directly).
__global__ __launch_bounds__(256) void k_nw(const float* __restrict__ w,
        const float* __restrict__ rs, const float* __restrict__ cs_part,
        const float* __restrict__ W1, const float* __restrict__ b1,
        const float* __restrict__ W2, const float* __restrict__ b2,
        const float* __restrict__ W3, const float* __restrict__ b3,
        unsigned short* __restrict__ Bt) {
    __shared__ float sW1[630], sW2[100], sb1[10], sb2[10], sw3[10], sa[10];
    __shared__ float rs_loc[32], cs_loc[32];
    __shared__ float rn_loc[320], cm_loc[320];
    __shared__ float st[32][33];   // +1 pad: conflict-free column reads
    int t = threadIdx.x;
    int n0 = (blockIdx.x & 31) * 32;   // weight-row base (k of gemm)
    int m0 = (blockIdx.x >> 5) * 32;   // weight-col base (n of gemm)
    const float inv = 1.0f / 1023.0f;

    for (int i = t; i < 630; i += 256) sW1[i] = W1[i];
    if (t < 100) sW2[t] = W2[t];
    if (t >= 128 && t < 138) { sb1[t - 128] = b1[t - 128]; sb2[t - 128] = b2[t - 128]; }
    if (t >= 160 && t < 170) sw3[t - 160] = W3[(t - 160) * 21];  // W3[:,0]
    if (t >= 192 && t < 224) rs_loc[t - 192] = rs[n0 + t - 192];
    if (t >= 224 && t < 256) {
        float s = 0.f;
        #pragma unroll
        for (int p = 0; p < 64; ++p) s += cs_part[(size_t)p * 1024 + m0 + (t - 224)];
        cs_loc[t - 224] = s;
    }
    float b30 = b3[0];
    __syncthreads();
    if (t < 10) sa[t] = sW1[t] - (sW1[10 + t] + sW1[20 + t]) * inv;
    // rn/cm tables for this block's 32 rows / 32 cols (640 values)
    for (int id = t; id < 640; id += 256) {
        int h = id % 10, i = (id / 10) & 31, side = id >= 320;
        if (!side) {
            int n = n0 + i;
            float v = rs_loc[i] * sW1[20 + h] * inv;
            #pragma unroll
            for (int j = 0; j < 10; j++) {
                float bit = (float)((n >> (9 - j)) & 1);
                v += bit * (sW1[(3 + j) * 10 + h] + sW1[(43 + j) * 10 + h]
                            - sW1[(23 + j) * 10 + h] * inv);
                v += (512.0f * inv) * sW1[(23 + j) * 10 + h];
            }
            rn_loc[i * 10 + h] = v;
        } else {
            int m = m0 + i;
            float v = cs_loc[i] * sW1[10 + h] * inv + sb1[h];
            #pragma unroll
            for (int j = 0; j < 10; j++) {
                float bit = (float)((m >> (9 - j)) & 1);
                v += bit * (sW1[(13 + j) * 10 + h] + sW1[(33 + j) * 10 + h]
                            - sW1[(53 + j) * 10 + h] * inv);
                v += (512.0f * inv) * sW1[(53 + j) * 10 + h];
            }
            cm_loc[i * 10 + h] = v;
        }
    }
    __syncthreads();
    int ml = t & 31;
    #pragma unroll
    for (int i = 0; i < 4; i++) {
        int nl = (t >> 5) + 8 * i;
        float wv = w[(size_t)(n0 + nl) * 1024 + m0 + ml];
        float h1[10];
        #pragma unroll
        for (int h = 0; h < 10; h++)
            h1[h] = fmaxf(wv * sa[h] + rn_loc[nl * 10 + h] + cm_loc[ml * 10 + h], 0.f);
        float u = b30;
        #pragma unroll
        for (int k = 0; k < 10; k++) {
            float h2 = sb2[k];
            #pragma unroll
            for (int h = 0; h < 10; h++) h2 += h1[h] * sW2[h * 10 + k];
            u += fmaxf(h2, 0.f) * sw3[k];
        }
        st[nl][ml] = wv + u;
    }
    __syncthreads();
    int mrow = t >> 3, kc = t & 7;
    unsigned short hi4[4];
    #pragma unroll
    for (int j = 0; j < 4; j++)
        hi4[j] = f2h(st[kc * 4 + j][mrow]);
    size_t base = (size_t)(m0 + mrow) * 1024 + n0 + kc * 4;
    *(ushort4*)&Bt[base] = make_ushort4(hi4[0], hi4[1], hi4[2], hi4[3]);
}

// ---------------------------------------------------------------------------
// K3 (R14): C = relu(X @ Wn) via single-phase fp16 MFMA; A staged from f32 X
// with in-register RNE f16 convert; epilogue writes f16 Ch.
// Tile 128(M)x64(N), BK=64, 4 waves, wave tile 64x32 (acc 4x2), LDS 24 KB.
// A-staging: per thread 4 chunks; f32 loads for iter t+1 issued BEFORE the
// compute barrier of iter t -> latency hides under 16 MFMAs; at the next
// iteration's ds_write the vmcnt wait is ~free. B stays global_load_lds.
// LDS layout identical to R13 (XOR-swizzled 16B chunks, pos = row*8 +
// (seg ^ (row&7))); frag reads unchanged.
// XCD-aware swizzle: XCD k owns m-groups {4k..4k+3} x all 16 n-blocks ->
// per-XCD working set A 2 MB f32 + B 2 MB ~ L2; Ch slice 1 MB stays dirty
// for the XCD-matched softmax reader.
__global__ __launch_bounds__(256, 3) void k_gemm14(const float* __restrict__ X,
        const unsigned short* __restrict__ Bt, unsigned short* __restrict__ Ch) {
    __shared__ unsigned short sAh[128 * 64];                  // 16 KB
    __shared__ unsigned short sBh[64 * 64];                   //  8 KB
    int tid = threadIdx.x;
    int lane = tid & 63, w = tid >> 6;
    // tile swizzle: b = (xcd, slot); ty = xcd*4 + slot/16, tx = slot%16
    int b = blockIdx.x;
    int xcd = b & 7, s = b >> 3;
    int ty = (xcd << 2) | (s >> 4);
    int tx = s & 15;
    int n0 = tx * 64, m0 = ty * 128;
    int wm = (w >> 1) * 64, wn = (w & 1) * 32;
    int quad = lane >> 4, l16 = lane & 15;

    f32x4 acc[4][2];
    #pragma unroll
    for (int i = 0; i < 4; i++)
        #pragma unroll
        for (int j = 0; j < 2; j++) acc[i][j] = (f32x4)0.f;

    // per-thread A chunk geometry (iter-independent):
    // chunk P = s2*256+tid -> row = P>>3, global seg = (P&7)^(row&7),
    // LDS dst element offset = P*8 (same linear layout global_load_lds used).
    int rowA[4], segA[4];
    #pragma unroll
    for (int s2 = 0; s2 < 4; ++s2) {
        int P = s2 * 256 + tid;
        rowA[s2] = P >> 3;
        segA[s2] = (P & 7) ^ (rowA[s2] & 7);
    }

    // prologue: issue A f32 loads for iter 0
    float4 pf0[4], pf1[4];
    #pragma unroll
    for (int s2 = 0; s2 < 4; ++s2) {
        const float* ga = &X[(size_t)(m0 + rowA[s2]) * 1024 + segA[s2] * 8];
        pf0[s2] = *(const float4*)(ga);
        pf1[s2] = *(const float4*)(ga + 4);
    }

    for (int it = 0; it < 16; ++it) {
        int kb = it * 64;
        __syncthreads();            // waves done reading LDS of it-1
        // A: convert prefetched f32 -> f16 (RNE), ds_write_b128.
        // vmcnt wait here covers only loads issued one iteration ago (~free).
        #pragma unroll
        for (int s2 = 0; s2 < 4; ++s2) {
            int P = s2 * 256 + tid;
            float4 a0 = pf0[s2], a1 = pf1[s2];
            f16x8 hv;
            hv[0] = (_Float16)a0.x; hv[1] = (_Float16)a0.y;
            hv[2] = (_Float16)a0.z; hv[3] = (_Float16)a0.w;
            hv[4] = (_Float16)a1.x; hv[5] = (_Float16)a1.y;
            hv[6] = (_Float16)a1.z; hv[7] = (_Float16)a1.w;
            *(f16x8*)&sAh[P * 8] = hv;
        }
        // B: 512 chunks (64 rows x 8 segs), 2 per thread, global_load_lds
        #pragma unroll
        for (int s2 = 0; s2 < 2; ++s2) {
            int P = s2 * 256 + tid;
            int row = P >> 3;
            int seg = (P & 7) ^ (row & 7);
            int ldsOff = (s2 * 256 + w * 64) * 8;       // wave-uniform dst
            size_t gb = (size_t)(n0 + row) * 1024 + kb + seg * 8;
            gld16(&Bt[gb], &sBh[ldsOff]);
        }
        // prefetch A for iter+1 (completes during MFMA below)
        if (it < 15) {
            int kb2 = kb + 64;
            #pragma unroll
            for (int s2 = 0; s2 < 4; ++s2) {
                const float* ga = &X[(size_t)(m0 + rowA[s2]) * 1024 + kb2 + segA[s2] * 8];
                pf0[s2] = *(const float4*)(ga);
                pf1[s2] = *(const float4*)(ga + 4);
            }
        }
        __syncthreads();            // drains lgkm (ds_write) + vmcnt (B, A-pf)
        #pragma unroll
        for (int ks = 0; ks < 2; ++ks) {
            int segk = ks * 4 + quad;
            f16x8 ah[4], bh[2];
            #pragma unroll
            for (int i = 0; i < 4; ++i) {
                int ra = wm + i * 16 + l16;
                int ca = (ra * 8 + (segk ^ (ra & 7))) * 8;
                ah[i] = *(const f16x8*)&sAh[ca];
            }
            #pragma unroll
            for (int j = 0; j < 2; ++j) {
                int rb = wn + j * 16 + l16;
                int cb = (rb * 8 + (segk ^ (rb & 7))) * 8;
                bh[j] = *(const f16x8*)&sBh[cb];
            }
            #pragma unroll
            for (int i = 0; i < 4; ++i)
                #pragma unroll
                for (int j = 0; j < 2; ++j)
                    acc[i][j] = __builtin_amdgcn_mfma_f32_16x16x32_f16(ah[i], bh[j], acc[i][j], 0, 0, 0);
        }
    }
    // C/D layout: col = lane&15, row = quad*4 + reg  [measured m89/m91]
    #pragma unroll
    for (int i = 0; i < 4; ++i) {
        int mr = m0 + wm + i * 16 + quad * 4;
        #pragma unroll
        for (int j = 0; j < 2; ++j) {
            int nc = n0 + wn + j * 16 + l16;
            #pragma unroll
            for (int r = 0; r < 4; ++r)
                Ch[(size_t)(mr + r) * 1024 + nc] = f2h(fmaxf(acc[i][j][r], 0.f));
        }
    }
}

// ---------------------------------------------------------------------------
// K4 (R13): row softmax, f16 in -> f32 out, shuffle-based (2 barriers).
// Block b -> row (b&7)*512 + (b>>3): reader XCD (b&7, round-robin dispatch)
// matches the gemm writer's XCD (row/512); the 1 MB/XCD f16 C slice is
// L2-resident -> the re-read avoids HBM.
__global__ __launch_bounds__(256) void k_softmax3(const unsigned short* __restrict__ Ch,
        float* __restrict__ out) {
    int b = blockIdx.x;
    int row = (b & 7) * 512 + (b >> 3);     // XCD-matched row
    int t = threadIdx.x, lane = t & 63, wv = t >> 6;
    __shared__ float red[8];
    ushort4 hv = *(const ushort4*)&Ch[(size_t)row * 1024 + t * 4];
    float4 v;
    v.x = h2f(hv.x); v.y = h2f(hv.y); v.z = h2f(hv.z); v.w = h2f(hv.w);
    float lm = fmaxf(fmaxf(v.x, v.y), fmaxf(v.z, v.w));
    #pragma unroll
    for (int o = 32; o; o >>= 1) lm = fmaxf(lm, __shfl_down(lm, o));
    if (lane == 0) red[wv] = lm;
    __syncthreads();
    float mx = fmaxf(fmaxf(red[0], red[1]), fmaxf(red[2], red[3]));
    float4 e;
    e.x = __expf(v.x - mx); e.y = __expf(v.y - mx);
    e.z = __expf(v.z - mx); e.w = __expf(v.w - mx);
    float ls = e.x + e.y + e.z + e.w;
    #pragma unroll
    for (int o = 32; o; o >>= 1) ls += __shfl_down(ls, o);
    if (lane == 0) red[4 + wv] = ls;
    __syncthreads();
    float inv = 1.0f / (red[4] + red[5] + red[6] + red[7]);
    e.x *= inv; e.y *= inv; e.z *= inv; e.w *= inv;
    *(float4*)&out[(size_t)row * 1024 + t * 4] = e;
}

// ---------------------------------------------------------------------------
extern "C" void kernel_launch(void* const* d_in, const int* in_sizes, int n_in,
                              void* d_out, int out_size, void* d_ws, size_t ws_size,
                              hipStream_t stream) {
    const float* X  = (const float*)d_in[0];
    const float* W  = (const float*)d_in[1];
    // d_in[2] = hidden: analytic, never read
    const float* W1 = (const float*)d_in[3];
    const float* b1 = (const float*)d_in[4];
    const float* W2 = (const float*)d_in[5];
    const float* b2 = (const float*)d_in[6];
    const float* W3 = (const float*)d_in[7];
    const float* b3 = (const float*)d_in[8];

    char* wsb = (char*)d_ws;
    float* rs            = (float*)(wsb + RS_OFF);
    float* cs_part       = (float*)(wsb + CSPART_OFF);
    unsigned short* Bt   = (unsigned short*)(wsb + BT_OFF);
    unsigned short* Ch   = (unsigned short*)(wsb + CH_OFF);
    float* out = (float*)d_out;

    k_pre<<<64, 256, 0, stream>>>(W, rs, cs_part);
    k_nw<<<1024, 256, 0, stream>>>(W, rs, cs_part, W1, b1, W2, b2, W3, b3, Bt);
    k_gemm14<<<512, 256, 0, stream>>>(X, Bt, Ch);
    k_softmax3<<<4096, 256, 0, stream>>>(Ch, out);
}

// Round 6
// 174.190 us; speedup vs baseline: 1.0612x; 1.0612x over previous
//
#include <hip/hip_runtime.h>
#include <hip/hip_bf16.h>
#include <stdint.h>

// out = softmax(relu(X @ new_weight)), new_weight = weight + MLP(feat)[...,0].
// hidden features collapse analytically to bit features of (n,m); layer-1 is
// rank-1 + separable -> per-row table rn[n][10] + per-col table cm[m][10],
// computed inline per k_nw block.
// R15 = R13 exact revert (best measured, 176.0us).
//   R14 post-mortem (184.9us, -8.9): (a) A-prefetch loads issued just before
//   __syncthreads were drained un-hidden (barrier emits vmcnt(0)); (b) f32 A
//   doubled L2 traffic (268 MB vs 134 MB) on cold X vs warm f16 Ah. Fixing
//   (a) needs raw s_barrier + counted vmcnt (race-risk) and (b) still caps
//   the gain at ~0-1us -> rejected; the Ah cast pass earns its bytes back.
// R13: fp16 intermediate C (Ch 8 MB instead of f32 16.8 MB) -> -2.2us,
//   matched prediction. Logits in [0,~6] -> f16 ulp <= 2^-8, absmax
//   unchanged at 3.9e-3 (threshold 1.2e-2).
// R11: cooperative fusion rejected (+139us grid-sync stall).
// Accounting (validated R11/R13/R14): ~148.5us = 3 harness poison fills is
//   the floor; our 4 kernels own ~27us (~12us irreducible HBM traffic +
//   latency-bound gemm + launches).
// GEMM core (R9): single-phase fp16: logit = fp16(x)*fp16(w).
//   Tile 128x64, BK=64, grid 512, XCD swizzle, XOR-swizzled LDS chunks,
//   cast-in-nw.
//
// 4 dispatches: k_pre (sums) -> k_nw (MLP + X cast) -> k_gemm13 -> k_softmax3.
//
// ws layout (bytes):
//   rs      @ 0        : f32[1024]          row sums of weight
//   cs_part @ 4096     : f32[64][1024]      per-block partial col sums
//   Bt      @ 266240   : f16[1024][1024]    new_weight^T         (2 MB)
//   Ah      @ 2363392  : f16[4096][1024]    fp16(X)              (8 MB)
//   Ch      @ 10752000 : f16[4096][1024]    f16 logits           (8 MB)

#define RS_OFF      0
#define CSPART_OFF  4096
#define BT_OFF      266240
#define AH_OFF      2363392
#define CH_OFF      10752000

typedef __attribute__((ext_vector_type(8))) _Float16 f16x8;
typedef __attribute__((ext_vector_type(4))) float f32x4;

__device__ __forceinline__ unsigned short f2h(float x) {
    _Float16 h = (_Float16)x;            // RNE
    unsigned short u;
    __builtin_memcpy(&u, &h, 2);
    return u;
}
__device__ __forceinline__ float h2f(unsigned short u) {
    _Float16 h;
    __builtin_memcpy(&h, &u, 2);
    return (float)h;
}
__device__ __forceinline__ void gld16(const void* g, void* l) {
    __builtin_amdgcn_global_load_lds(
        (const __attribute__((address_space(1))) unsigned*)g,
        (__attribute__((address_space(3))) unsigned*)l, 16, 0, 0);
}

// ---------------------------------------------------------------------------
// K1: row sums (wave per 4 rows, shuffle) + 64 partial colsum vectors.
__global__ __launch_bounds__(256) void k_pre(const float* __restrict__ w,
        float* __restrict__ rs, float* __restrict__ cs_part) {
    __shared__ float part[4][1024];
    int t = threadIdx.x;
    int lane = t & 63, wv = t >> 6;
    int r0 = blockIdx.x * 16 + wv * 4;
    float ccol[16];
    #pragma unroll
    for (int j = 0; j < 16; ++j) ccol[j] = 0.f;
    #pragma unroll
    for (int rr = 0; rr < 4; ++rr) {
        int row = r0 + rr;
        float rsum = 0.f;
        #pragma unroll
        for (int j = 0; j < 16; ++j) {
            float v = w[(size_t)row * 1024 + j * 64 + lane];
            ccol[j] += v;
            rsum += v;
        }
        #pragma unroll
        for (int o = 32; o; o >>= 1) rsum += __shfl_down(rsum, o);
        if (lane == 0) rs[row] = rsum;
    }
    #pragma unroll
    for (int j = 0; j < 16; ++j) part[wv][j * 64 + lane] = ccol[j];
    __syncthreads();
    #pragma unroll
    for (int j = 0; j < 4; ++j) {
        int c = t + j * 256;
        cs_part[(size_t)blockIdx.x * 1024 + c] =
            part[0][c] + part[1][c] + part[2][c] + part[3][c];
    }
}

// ---------------------------------------------------------------------------
// K2: blocks 0..1023: new_weight MLP on 32x32 tiles (inline rn/cm tables +
// colsum reduction), writing TRANSPOSED fp16 Bt[m][n]. Blocks 1024..2047:
// cast X -> fp16 Ah (memory-bound; overlaps the compute-bound MLP blocks).
// Cast rows XCD-matched to the gemm A-reader: cast block b2x (XCD b2x&7)
// handles X rows (b2x&7)*512 + (b2x>>3)*4 .. +3.
__global__ __launch_bounds__(256) void k_nw(const float* __restrict__ w,
        const float* __restrict__ X,
        const float* __restrict__ rs, const float* __restrict__ cs_part,
        const float* __restrict__ W1, const float* __restrict__ b1,
        const float* __restrict__ W2, const float* __restrict__ b2,
        const float* __restrict__ W3, const float* __restrict__ b3,
        unsigned short* __restrict__ Bt, unsigned short* __restrict__ Ah) {
    __shared__ float sW1[630], sW2[100], sb1[10], sb2[10], sw3[10], sa[10];
    __shared__ float rs_loc[32], cs_loc[32];
    __shared__ float rn_loc[320], cm_loc[320];
    __shared__ float st[32][33];   // +1 pad: conflict-free column reads
    int t = threadIdx.x;
    if (blockIdx.x >= 1024) {
        int b2x = blockIdx.x - 1024;        // 0..1023, 4 X-rows each
        int rb = (b2x & 7) * 512 + (b2x >> 3) * 4;   // XCD-matched row base
        size_t rbase = (size_t)rb * 1024;
        #pragma unroll
        for (int p = 0; p < 4; ++p) {
            size_t idx = rbase + p * 1024 + t * 4;
            float4 v = *(const float4*)&X[idx];
            ushort4 h;
            h.x = f2h(v.x); h.y = f2h(v.y); h.z = f2h(v.z); h.w = f2h(v.w);
            *(ushort4*)&Ah[idx] = h;
        }
        return;
    }
    int n0 = (blockIdx.x & 31) * 32;   // weight-row base (k of gemm)
    int m0 = (blockIdx.x >> 5) * 32;   // weight-col base (n of gemm)
    const float inv = 1.0f / 1023.0f;

    for (int i = t; i < 630; i += 256) sW1[i] = W1[i];
    if (t < 100) sW2[t] = W2[t];
    if (t >= 128 && t < 138) { sb1[t - 128] = b1[t - 128]; sb2[t - 128] = b2[t - 128]; }
    if (t >= 160 && t < 170) sw3[t - 160] = W3[(t - 160) * 21];  // W3[:,0]
    if (t >= 192 && t < 224) rs_loc[t - 192] = rs[n0 + t - 192];
    if (t >= 224 && t < 256) {
        float s = 0.f;
        #pragma unroll
        for (int p = 0; p < 64; ++p) s += cs_part[(size_t)p * 1024 + m0 + (t - 224)];
        cs_loc[t - 224] = s;
    }
    float b30 = b3[0];
    __syncthreads();
    if (t < 10) sa[t] = sW1[t] - (sW1[10 + t] + sW1[20 + t]) * inv;
    // rn/cm tables for this block's 32 rows / 32 cols (640 values)
    for (int id = t; id < 640; id += 256) {
        int h = id % 10, i = (id / 10) & 31, side = id >= 320;
        if (!side) {
            int n = n0 + i;
            float v = rs_loc[i] * sW1[20 + h] * inv;
            #pragma unroll
            for (int j = 0; j < 10; j++) {
                float bit = (float)((n >> (9 - j)) & 1);
                v += bit * (sW1[(3 + j) * 10 + h] + sW1[(43 + j) * 10 + h]
                            - sW1[(23 + j) * 10 + h] * inv);
                v += (512.0f * inv) * sW1[(23 + j) * 10 + h];
            }
            rn_loc[i * 10 + h] = v;
        } else {
            int m = m0 + i;
            float v = cs_loc[i] * sW1[10 + h] * inv + sb1[h];
            #pragma unroll
            for (int j = 0; j < 10; j++) {
                float bit = (float)((m >> (9 - j)) & 1);
                v += bit * (sW1[(13 + j) * 10 + h] + sW1[(33 + j) * 10 + h]
                            - sW1[(53 + j) * 10 + h] * inv);
                v += (512.0f * inv) * sW1[(53 + j) * 10 + h];
            }
            cm_loc[i * 10 + h] = v;
        }
    }
    __syncthreads();
    int ml = t & 31;
    #pragma unroll
    for (int i = 0; i < 4; i++) {
        int nl = (t >> 5) + 8 * i;
        float wv = w[(size_t)(n0 + nl) * 1024 + m0 + ml];
        float h1[10];
        #pragma unroll
        for (int h = 0; h < 10; h++)
            h1[h] = fmaxf(wv * sa[h] + rn_loc[nl * 10 + h] + cm_loc[ml * 10 + h], 0.f);
        float u = b30;
        #pragma unroll
        for (int k = 0; k < 10; k++) {
            float h2 = sb2[k];
            #pragma unroll
            for (int h = 0; h < 10; h++) h2 += h1[h] * sW2[h * 10 + k];
            u += fmaxf(h2, 0.f) * sw3[k];
        }
        st[nl][ml] = wv + u;
    }
    __syncthreads();
    int mrow = t >> 3, kc = t & 7;
    unsigned short hi4[4];
    #pragma unroll
    for (int j = 0; j < 4; j++)
        hi4[j] = f2h(st[kc * 4 + j][mrow]);
    size_t base = (size_t)(m0 + mrow) * 1024 + n0 + kc * 4;
    *(ushort4*)&Bt[base] = make_ushort4(hi4[0], hi4[1], hi4[2], hi4[3]);
}

// ---------------------------------------------------------------------------
// K3: C = relu(X @ Wn) via single-phase fp16 MFMA; epilogue writes f16 Ch.
// Tile 128(M)x64(N), BK=64, 4 waves, wave tile 64x32 (acc 4x2), LDS 24 KB.
// XCD-aware swizzle: XCD k owns m-groups {4k..4k+3} x all 16 n-blocks ->
// per-XCD working set A 1 MB + B 2 MB stays L2-resident; Ch slice 1 MB stays
// dirty-resident for the XCD-matched softmax reader.
// XOR-swizzled LDS chunks (pos = row*8 + (seg ^ (row&7))): staging stays
// lane-contiguous for global_load_lds, frag reads spread over all bank-quads.
__global__ __launch_bounds__(256, 3) void k_gemm13(const unsigned short* __restrict__ Ah,
        const unsigned short* __restrict__ Bt, unsigned short* __restrict__ Ch) {
    __shared__ unsigned short sAh[128 * 64];                  // 16 KB
    __shared__ unsigned short sBh[64 * 64];                   //  8 KB
    int tid = threadIdx.x;
    int lane = tid & 63, w = tid >> 6;
    // tile swizzle: b = (xcd, slot); ty = xcd*4 + slot/16, tx = slot%16
    int b = blockIdx.x;
    int xcd = b & 7, s = b >> 3;
    int ty = (xcd << 2) | (s >> 4);
    int tx = s & 15;
    int n0 = tx * 64, m0 = ty * 128;
    int wm = (w >> 1) * 64, wn = (w & 1) * 32;
    int quad = lane >> 4, l16 = lane & 15;

    f32x4 acc[4][2];
    #pragma unroll
    for (int i = 0; i < 4; i++)
        #pragma unroll
        for (int j = 0; j < 2; j++) acc[i][j] = (f32x4)0.f;

    for (int it = 0; it < 16; ++it) {
        int kb = it * 64;
        __syncthreads();
        // A: 1024 chunks (128 rows x 8 segs), 4 per thread
        #pragma unroll
        for (int s2 = 0; s2 < 4; ++s2) {
            int P = s2 * 256 + tid;
            int row = P >> 3;
            int seg = (P & 7) ^ (row & 7);
            int ldsOff = (s2 * 256 + w * 64) * 8;       // wave-uniform dst
            size_t ga = (size_t)(m0 + row) * 1024 + kb + seg * 8;
            gld16(&Ah[ga], &sAh[ldsOff]);
        }
        // B: 512 chunks (64 rows x 8 segs), 2 per thread
        #pragma unroll
        for (int s2 = 0; s2 < 2; ++s2) {
            int P = s2 * 256 + tid;
            int row = P >> 3;
            int seg = (P & 7) ^ (row & 7);
            int ldsOff = (s2 * 256 + w * 64) * 8;
            size_t gb = (size_t)(n0 + row) * 1024 + kb + seg * 8;
            gld16(&Bt[gb], &sBh[ldsOff]);
        }
        __syncthreads();
        #pragma unroll
        for (int ks = 0; ks < 2; ++ks) {
            int segk = ks * 4 + quad;
            f16x8 ah[4], bh[2];
            #pragma unroll
            for (int i = 0; i < 4; ++i) {
                int ra = wm + i * 16 + l16;
                int ca = (ra * 8 + (segk ^ (ra & 7))) * 8;
                ah[i] = *(const f16x8*)&sAh[ca];
            }
            #pragma unroll
            for (int j = 0; j < 2; ++j) {
                int rb = wn + j * 16 + l16;
                int cb = (rb * 8 + (segk ^ (rb & 7))) * 8;
                bh[j] = *(const f16x8*)&sBh[cb];
            }
            #pragma unroll
            for (int i = 0; i < 4; ++i)
                #pragma unroll
                for (int j = 0; j < 2; ++j)
                    acc[i][j] = __builtin_amdgcn_mfma_f32_16x16x32_f16(ah[i], bh[j], acc[i][j], 0, 0, 0);
        }
    }
    // C/D layout: col = lane&15, row = quad*4 + reg  [measured m89/m91]
    // f16 epilogue: per (i,r) a quad's 16 lanes write 32 contiguous bytes.
    #pragma unroll
    for (int i = 0; i < 4; ++i) {
        int mr = m0 + wm + i * 16 + quad * 4;
        #pragma unroll
        for (int j = 0; j < 2; ++j) {
            int nc = n0 + wn + j * 16 + l16;
            #pragma unroll
            for (int r = 0; r < 4; ++r)
                Ch[(size_t)(mr + r) * 1024 + nc] = f2h(fmaxf(acc[i][j][r], 0.f));
        }
    }
}

// ---------------------------------------------------------------------------
// K4: row softmax, f16 in -> f32 out, shuffle-based (2 barriers).
// Block b -> row (b&7)*512 + (b>>3): reader XCD (b&7, round-robin dispatch)
// matches the gemm writer's XCD (row/512); the 1 MB/XCD f16 C slice is
// L2-resident -> the re-read avoids HBM.
__global__ __launch_bounds__(256) void k_softmax3(const unsigned short* __restrict__ Ch,
        float* __restrict__ out) {
    int b = blockIdx.x;
    int row = (b & 7) * 512 + (b >> 3);     // XCD-matched row
    int t = threadIdx.x, lane = t & 63, wv = t >> 6;
    __shared__ float red[8];
    ushort4 hv = *(const ushort4*)&Ch[(size_t)row * 1024 + t * 4];
    float4 v;
    v.x = h2f(hv.x); v.y = h2f(hv.y); v.z = h2f(hv.z); v.w = h2f(hv.w);
    float lm = fmaxf(fmaxf(v.x, v.y), fmaxf(v.z, v.w));
    #pragma unroll
    for (int o = 32; o; o >>= 1) lm = fmaxf(lm, __shfl_down(lm, o));
    if (lane == 0) red[wv] = lm;
    __syncthreads();
    float mx = fmaxf(fmaxf(red[0], red[1]), fmaxf(red[2], red[3]));
    float4 e;
    e.x = __expf(v.x - mx); e.y = __expf(v.y - mx);
    e.z = __expf(v.z - mx); e.w = __expf(v.w - mx);
    float ls = e.x + e.y + e.z + e.w;
    #pragma unroll
    for (int o = 32; o; o >>= 1) ls += __shfl_down(ls, o);
    if (lane == 0) red[4 + wv] = ls;
    __syncthreads();
    float inv = 1.0f / (red[4] + red[5] + red[6] + red[7]);
    e.x *= inv; e.y *= inv; e.z *= inv; e.w *= inv;
    *(float4*)&out[(size_t)row * 1024 + t * 4] = e;
}

// ---------------------------------------------------------------------------
extern "C" void kernel_launch(void* const* d_in, const int* in_sizes, int n_in,
                              void* d_out, int out_size, void* d_ws, size_t ws_size,
                              hipStream_t stream) {
    const float* X  = (const float*)d_in[0];
    const float* W  = (const float*)d_in[1];
    // d_in[2] = hidden: analytic, never read
    const float* W1 = (const float*)d_in[3];
    const float* b1 = (const float*)d_in[4];
    const float* W2 = (const float*)d_in[5];
    const float* b2 = (const float*)d_in[6];
    const float* W3 = (const float*)d_in[7];
    const float* b3 = (const float*)d_in[8];

    char* wsb = (char*)d_ws;
    float* rs            = (float*)(wsb + RS_OFF);
    float* cs_part       = (float*)(wsb + CSPART_OFF);
    unsigned short* Bt   = (unsigned short*)(wsb + BT_OFF);
    unsigned short* Ah   = (unsigned short*)(wsb + AH_OFF);
    unsigned short* Ch   = (unsigned short*)(wsb + CH_OFF);
    float* out = (float*)d_out;

    k_pre<<<64, 256, 0, stream>>>(W, rs, cs_part);
    k_nw<<<2048, 256, 0, stream>>>(W, X, rs, cs_part, W1, b1, W2, b2, W3, b3, Bt, Ah);
    k_gemm13<<<512, 256, 0, stream>>>(Ah, Bt, Ch);
    k_softmax3<<<4096, 256, 0, stream>>>(Ch, out);
}